// Round 9
// baseline (525.481 us; speedup 1.0000x reference)
//
#include <hip/hip_runtime.h>

#define T_TOK 1024
#define H_DIM 1024
#define I_DIM 768
#define E_NUM 8

// ---- work-queue geometry ----
#define NWORK 768            // persistent workers (3/CU with 49.4 KB LDS)
#define N_ILV 2304           // 96 pairs * (8 dq13 + 16 gemm1 tiles)
#define N_ZERO 64
#define N_W2DQ 384
#define N_G2   1024
#define Q_ZERO N_ILV
#define Q_W2DQ (N_ILV + N_ZERO)
#define Q_G2   (N_ILV + N_ZERO + N_W2DQ)
#define NITEMS (N_ILV + N_ZERO + N_W2DQ + N_G2)   // 3776

#define SLOT 24576           // ring slot: B 16KB + A 8KB
#define A_OFF 16384

// ctrl indices (stride-16 ints to avoid cacheline ping-pong)
#define C_QHEAD 0
#define C_ZCNT  16
#define C_W2CNT 32
#define C_PAIR(P)  (48 + (P) * 16)      // 96 pair flags
#define C_STRIP(s) (1584 + (s) * 16)    // 128 strip flags
#define C_TOTAL 3632

typedef __bf16 bf16x8 __attribute__((ext_vector_type(8)));
typedef float  f32x4  __attribute__((ext_vector_type(4)));

__device__ inline bf16x8 cvt8(float4 a, float4 b, float s) {
    bf16x8 o;
    o[0] = (__bf16)(a.x * s); o[1] = (__bf16)(a.y * s);
    o[2] = (__bf16)(a.z * s); o[3] = (__bf16)(a.w * s);
    o[4] = (__bf16)(b.x * s); o[5] = (__bf16)(b.y * s);
    o[6] = (__bf16)(b.z * s); o[7] = (__bf16)(b.w * s);
    return o;
}

__device__ inline void async16(const void* g, void* l) {
    __builtin_amdgcn_global_load_lds(
        (const __attribute__((address_space(1))) unsigned int*)g,
        (__attribute__((address_space(3))) unsigned int*)l, 16, 0, 0);
}

#define VM_WAIT6  asm volatile("s_waitcnt vmcnt(6)"  ::: "memory")
#define VM_WAIT0  asm volatile("s_waitcnt vmcnt(0)"  ::: "memory")
#define MFMA(A, B, C) __builtin_amdgcn_mfma_f32_16x16x32_bf16(A, B, C, 0, 0, 0)

struct StgEnt { const char* p; int l; };

// ---- L1: x -> bf16 (512 blocks) + router + ctrl zero (block 512) ---------
__global__ __launch_bounds__(256) void prep_lite(
    const float* __restrict__ x, const float* __restrict__ logits,
    __bf16* __restrict__ xbf,
    int* __restrict__ counts, int* __restrict__ base,
    int* __restrict__ tok_list, float* __restrict__ wt_list,
    int* __restrict__ ctrl)
{
    const int bx = blockIdx.x;
    if (bx < 512) {
        int g = bx * 256 + threadIdx.x;   // < 131072
        const float4* src = (const float4*)x + (size_t)g * 2;
        *(bf16x8*)(xbf + (size_t)g * 8) = cvt8(src[0], src[1], 1.0f);
        return;
    }
    // ---- ctrl zero + router (single block) ----
    const int t0 = threadIdx.x;
    for (int i = t0; i < C_TOTAL; i += 256) ctrl[i] = 0;
    __shared__ int cnt[E_NUM];
    if (t0 < E_NUM) cnt[t0] = 0;
    __syncthreads();
#pragma unroll
    for (int tt = 0; tt < 4; tt++) {
        int t = t0 + tt * 256;
        float l[E_NUM];
#pragma unroll
        for (int e = 0; e < E_NUM; e++) l[e] = logits[t * E_NUM + e];
        int e0 = 0; float m0 = l[0];
#pragma unroll
        for (int e = 1; e < E_NUM; e++) if (l[e] > m0) { m0 = l[e]; e0 = e; }
        int e1 = -1; float m1 = -3e38f;
#pragma unroll
        for (int e = 0; e < E_NUM; e++) if (e != e0 && l[e] > m1) { m1 = l[e]; e1 = e; }
        float w0 = 1.0f / (1.0f + expf(m1 - m0));
        float w1 = 1.0f - w0;
        int p0 = atomicAdd(&cnt[e0], 1);
        tok_list[e0 * T_TOK + p0] = t;
        wt_list[e0 * T_TOK + p0] = w0;
        int p1 = atomicAdd(&cnt[e1], 1);
        tok_list[e1 * T_TOK + p1] = t;
        wt_list[e1 * T_TOK + p1] = w1;
    }
    __syncthreads();
    if (t0 == 0) {
        int s = 0;
        for (int e = 0; e < E_NUM; e++) { base[e] = s; counts[e] = cnt[e]; s += cnt[e]; }
    }
}

// ---- L2: persistent work-queue kernel ------------------------------------
// Items (in-order queue; every gate references strictly-earlier items =>
// provably deadlock-free regardless of dispatch order / residency):
//   [P*24 .. P*24+7]  : dequant w13 panel P (16 rows each)  -> pairflag[P]
//   [P*24+8 .. +23]   : gemm1 tile (P, m), gated pairflag==8 -> strip[e,m]
//   [2304 .. 2367]    : out zero                             -> zcnt
//   [2368 .. 2751]    : dequant w2                           -> w2cnt
//   [2752 .. 3775]    : gemm2 tile, gated zcnt/w2cnt/strip==12
__global__ __launch_bounds__(256, 3) void moe_queue(
    const float* __restrict__ w13, const float* __restrict__ w13s,
    const float* __restrict__ w2,  const float* __restrict__ w2s,
    const __bf16* __restrict__ xbf,
    __bf16* __restrict__ w13d, __bf16* __restrict__ w2d,
    const int* __restrict__ counts, const int* __restrict__ base,
    const int* __restrict__ tok_list, const float* __restrict__ wt_list,
    __bf16* __restrict__ act, float* __restrict__ out,
    int* __restrict__ ctrl)
{
    __shared__ union { uint4 r4[2 * SLOT / 16]; float gu[64 * 132]; } u;  // 49152 B
    __shared__ int tokS[64];
    __shared__ int curs;
    char* ring = (char*)u.r4;
    const int tid = threadIdx.x;

    for (;;) {
        __syncthreads();                       // LDS + curs reuse guard
        if (tid == 0) curs = atomicAdd(&ctrl[C_QHEAD], 1);
        __syncthreads();
        const int item = curs;
        if (item >= NITEMS) return;

        if (item < N_ILV) {
            const int P = item / 24, s = item % 24;
            const int e = P / 12, nb = P % 12;
            if (s < 8) {
                // ---- dequant w13, 16 rows of panel P ----
                const int n0rel = (s < 4) ? (nb * 64 + s * 16)
                                          : (I_DIM + nb * 64 + (s - 4) * 16);
                const size_t gb = (size_t)(e * 1536 + n0rel) * 128;
#pragma unroll
                for (int k = 0; k < 8; k++) {
                    size_t g = gb + k * 256 + tid;
                    int row = (int)(g >> 7), k8 = (int)(g & 127);
                    float sc = w13s[(row << 3) | (k8 >> 4)];
                    const float4* src = (const float4*)w13 + g * 2;
                    *(bf16x8*)(w13d + g * 8) = cvt8(src[0], src[1], sc);
                }
                __threadfence(); __syncthreads();
                if (tid == 0) atomicAdd(&ctrl[C_PAIR(P)], 1);
            } else {
                // ---- gemm1 tile (P, m=s-8): M64 x N128, K=16*64 ----
                const int m = s - 8;
                const int count = counts[e];
                const int m0 = m * 64;
                if (m0 < count) {
                    const int n0 = nb * 64;
                    const int abase = base[e];
                    if (tid == 0) {
                        while (atomicAdd(&ctrl[C_PAIR(P)], 0) < 8)
                            __builtin_amdgcn_s_sleep(2);
                    }
                    __syncthreads();
                    __threadfence();           // acquire: L1 invalidate

                    if (tid < 64) {
                        int r = m0 + tid;
                        tokS[tid] = (r < count) ? tok_list[e * T_TOK + r]
                                                : tok_list[e * T_TOK];
                    }
                    __syncthreads();

                    const int wv = tid >> 6, ln = tid & 63;
                    StgEnt se[6];
#pragma unroll
                    for (int j = 0; j < 6; j++) {
                        int off = wv * 6144 + j * 1024 + ln * 16;
                        se[j].l = wv * 6144 + j * 1024;
                        if (off < A_OFF) {
                            int r = off >> 7, sl = (off >> 4) & 7, g = sl ^ (r & 7);
                            int nB = (r < 64) ? (n0 + r) : (I_DIM + n0 + r - 64);
                            se[j].p = (const char*)w13d + ((size_t)e * 2 * I_DIM + nB) * 2048 + g * 16;
                        } else {
                            int ao = off - A_OFF, r = ao >> 7, sl = (ao >> 4) & 7, g = sl ^ (r & 7);
                            se[j].p = (const char*)xbf + (size_t)tokS[r] * 2048 + g * 16;
                        }
                    }

#define ISSUE1(kc, sb) do { \
        async16(se[0].p + (kc) * 128, (sb) + se[0].l); \
        async16(se[1].p + (kc) * 128, (sb) + se[1].l); \
        async16(se[2].p + (kc) * 128, (sb) + se[2].l); \
        async16(se[3].p + (kc) * 128, (sb) + se[3].l); \
        async16(se[4].p + (kc) * 128, (sb) + se[4].l); \
        async16(se[5].p + (kc) * 128, (sb) + se[5].l); } while (0)

                    const int wid = wv, lane = ln, lrow = lane & 15, quad = lane >> 4;
                    int aoff[2][4], boff[2][2];
#pragma unroll
                    for (int kk = 0; kk < 2; kk++) {
                        int gph = ((kk * 4 + quad) ^ (lrow & 7)) << 4;
#pragma unroll
                        for (int i = 0; i < 4; i++) aoff[kk][i] = (i * 16 + lrow) * 128 + gph;
#pragma unroll
                        for (int j = 0; j < 2; j++) boff[kk][j] = (wid * 32 + j * 16 + lrow) * 128 + gph;
                    }

                    f32x4 acc[4][2];
#pragma unroll
                    for (int i = 0; i < 4; i++)
#pragma unroll
                        for (int j = 0; j < 2; j++) { f32x4 z = {0.f, 0.f, 0.f, 0.f}; acc[i][j] = z; }

                    auto compute = [&](const char* sb) {
                        const char* Bb = sb;
                        const char* Ab = sb + A_OFF;
#pragma unroll
                        for (int kk = 0; kk < 2; kk++) {
                            bf16x8 b0 = *(const bf16x8*)(Bb + boff[kk][0]);
                            bf16x8 b1 = *(const bf16x8*)(Bb + boff[kk][1]);
#pragma unroll
                            for (int i = 0; i < 4; i++) {
                                bf16x8 a = *(const bf16x8*)(Ab + aoff[kk][i]);
                                acc[i][0] = MFMA(a, b0, acc[i][0]);
                                acc[i][1] = MFMA(a, b1, acc[i][1]);
                            }
                        }
                    };

                    VM_WAIT0;   // exact vmcnt baseline
                    ISSUE1(0, ring);
#pragma unroll
                    for (int k = 0; k < 16; k++) {
                        if (k + 1 < 16) ISSUE1(k + 1, ring + ((k + 1) & 1) * SLOT);
                        if (k < 15) { VM_WAIT6; } else { VM_WAIT0; }
                        __builtin_amdgcn_s_barrier();
                        compute(ring + (k & 1) * SLOT);
                        __builtin_amdgcn_s_barrier();
                    }
#undef ISSUE1

#pragma unroll
                    for (int i = 0; i < 4; i++)
#pragma unroll
                        for (int j = 0; j < 2; j++)
#pragma unroll
                            for (int r = 0; r < 4; r++) {
                                int mr = i * 16 + quad * 4 + r;
                                int c = wid * 32 + j * 16 + lrow;
                                u.gu[mr * 132 + c] = acc[i][j][r];
                            }
                    __syncthreads();

#pragma unroll
                    for (int ii = 0; ii < 16; ii++) {
                        int o = ii * 256 + tid;
                        int mr = o >> 6, c = o & 63;
                        if (m0 + mr < count) {
                            float g  = u.gu[mr * 132 + c];
                            float up = u.gu[mr * 132 + 64 + c];
                            float a  = g / (1.0f + expf(-g)) * up;
                            act[(size_t)(abase + m0 + mr) * I_DIM + n0 + c] = (__bf16)a;
                        }
                    }
                    __threadfence(); __syncthreads();
                    if (tid == 0) atomicAdd(&ctrl[C_STRIP(e * 16 + m)], 1);
                }
            }
        } else if (item < Q_W2DQ) {
            // ---- out zero ----
            float4* out4 = (float4*)out;
            float4 z = make_float4(0.f, 0.f, 0.f, 0.f);
            const int zi = item - Q_ZERO;
#pragma unroll
            for (int k = 0; k < 8; k++) {
                size_t go = (size_t)zi * 2048 + k * 256 + tid;
                out4[2 * go] = z; out4[2 * go + 1] = z;
            }
            __threadfence(); __syncthreads();
            if (tid == 0) atomicAdd(&ctrl[C_ZCNT], 1);
        } else if (item < Q_G2) {
            // ---- dequant w2 ----
            const int q = item - Q_W2DQ;
#pragma unroll
            for (int k = 0; k < 8; k++) {
                int g2 = q * 2048 + k * 256 + tid;      // < 786432
                unsigned row = (unsigned)g2 / 96u;
                int k8 = g2 - row * 96;
                float sc = w2s[row * 6 + (k8 >> 4)];
                const float4* src = (const float4*)w2 + (size_t)g2 * 2;
                *(bf16x8*)(w2d + (size_t)g2 * 8) = cvt8(src[0], src[1], sc);
            }
            __threadfence(); __syncthreads();
            if (tid == 0) atomicAdd(&ctrl[C_W2CNT], 1);
        } else {
            // ---- gemm2 tile: M64 x N128, K=12*64 ----
            const int idx2 = item - Q_G2;
            const int xcd = idx2 & 7, t2 = idx2 >> 3;
            const int p2 = t2 & 7, m = t2 >> 3;
            const int P2 = xcd + 8 * p2;
            const int nb = P2 & 7, e = P2 >> 3;
            const int count = counts[e];
            const int m0 = m * 64;
            if (m0 < count) {
                const int n0 = nb * 128;
                const int abase = base[e];
                if (tid == 0) {
                    while (atomicAdd(&ctrl[C_ZCNT], 0) < N_ZERO)  __builtin_amdgcn_s_sleep(2);
                    while (atomicAdd(&ctrl[C_W2CNT], 0) < N_W2DQ) __builtin_amdgcn_s_sleep(2);
                    while (atomicAdd(&ctrl[C_STRIP(e * 16 + m)], 0) < 12) __builtin_amdgcn_s_sleep(2);
                }
                __syncthreads();
                __threadfence();               // acquire: L1 invalidate

                const int wv = tid >> 6, ln = tid & 63;
                StgEnt se[6];
#pragma unroll
                for (int j = 0; j < 6; j++) {
                    int off = wv * 6144 + j * 1024 + ln * 16;
                    se[j].l = wv * 6144 + j * 1024;
                    if (off < A_OFF) {
                        int r = off >> 7, sl = (off >> 4) & 7, g = sl ^ (r & 7);
                        se[j].p = (const char*)w2d + ((size_t)e * H_DIM + n0 + r) * 1536 + g * 16;
                    } else {
                        int ao = off - A_OFF, r = ao >> 7, sl = (ao >> 4) & 7, g = sl ^ (r & 7);
                        int gr = abase + m0 + r; if (gr > 2 * T_TOK - 1) gr = 2 * T_TOK - 1;
                        se[j].p = (const char*)act + (size_t)gr * 1536 + g * 16;
                    }
                }

#define ISSUE2(kc, sb) do { \
        async16(se[0].p + (kc) * 128, (sb) + se[0].l); \
        async16(se[1].p + (kc) * 128, (sb) + se[1].l); \
        async16(se[2].p + (kc) * 128, (sb) + se[2].l); \
        async16(se[3].p + (kc) * 128, (sb) + se[3].l); \
        async16(se[4].p + (kc) * 128, (sb) + se[4].l); \
        async16(se[5].p + (kc) * 128, (sb) + se[5].l); } while (0)

                const int wid = wv, lane = ln, lrow = lane & 15, quad = lane >> 4;
                int aoff[2][4], boff[2][2];
#pragma unroll
                for (int kk = 0; kk < 2; kk++) {
                    int gph = ((kk * 4 + quad) ^ (lrow & 7)) << 4;
#pragma unroll
                    for (int i = 0; i < 4; i++) aoff[kk][i] = (i * 16 + lrow) * 128 + gph;
#pragma unroll
                    for (int j = 0; j < 2; j++) boff[kk][j] = (wid * 32 + j * 16 + lrow) * 128 + gph;
                }

                f32x4 acc[4][2];
#pragma unroll
                for (int i = 0; i < 4; i++)
#pragma unroll
                    for (int j = 0; j < 2; j++) { f32x4 z = {0.f, 0.f, 0.f, 0.f}; acc[i][j] = z; }

                auto compute2 = [&](const char* sb) {
                    const char* Bb = sb;
                    const char* Ab = sb + A_OFF;
#pragma unroll
                    for (int kk = 0; kk < 2; kk++) {
                        bf16x8 b0 = *(const bf16x8*)(Bb + boff[kk][0]);
                        bf16x8 b1 = *(const bf16x8*)(Bb + boff[kk][1]);
#pragma unroll
                        for (int i = 0; i < 4; i++) {
                            bf16x8 a = *(const bf16x8*)(Ab + aoff[kk][i]);
                            acc[i][0] = MFMA(a, b0, acc[i][0]);
                            acc[i][1] = MFMA(a, b1, acc[i][1]);
                        }
                    }
                };

                VM_WAIT0;
                ISSUE2(0, ring);
#pragma unroll
                for (int k = 0; k < 12; k++) {
                    if (k + 1 < 12) ISSUE2(k + 1, ring + ((k + 1) & 1) * SLOT);
                    if (k < 11) { VM_WAIT6; } else { VM_WAIT0; }
                    __builtin_amdgcn_s_barrier();
                    compute2(ring + (k & 1) * SLOT);
                    __builtin_amdgcn_s_barrier();
                }
#undef ISSUE2

#pragma unroll
                for (int i = 0; i < 4; i++)
#pragma unroll
                    for (int r = 0; r < 4; r++) {
                        int mr = i * 16 + quad * 4 + r;
                        if (m0 + mr < count) {
                            int   tk = tok_list[e * T_TOK + m0 + mr];
                            float w  = wt_list[e * T_TOK + m0 + mr];
#pragma unroll
                            for (int j = 0; j < 2; j++) {
                                int h = n0 + wid * 32 + j * 16 + lrow;
                                atomicAdd(&out[(size_t)tk * H_DIM + h], w * acc[i][j][r]);
                            }
                        }
                    }
            }
        }
    }
}

extern "C" void kernel_launch(void* const* d_in, const int* in_sizes, int n_in,
                              void* d_out, int out_size, void* d_ws, size_t ws_size,
                              hipStream_t stream) {
    (void)in_sizes; (void)n_in; (void)out_size; (void)ws_size;
    const float* x      = (const float*)d_in[0];
    const float* logits = (const float*)d_in[1];
    const float* w13    = (const float*)d_in[2];
    const float* w13s   = (const float*)d_in[3];
    const float* w2     = (const float*)d_in[4];
    const float* w2s    = (const float*)d_in[5];
    float* out = (float*)d_out;

    char* ws = (char*)d_ws;
    int*    counts   = (int*)ws;                              // @0
    int*    base     = (int*)(ws + 128);                      // @128
    int*    tok_list = (int*)(ws + 256);                      // 32 KB
    float*  wt_list  = (float*)(ws + 256 + 32768);            // 32 KB
    __bf16* act      = (__bf16*)(ws + 65792);                 // 3 MB
    __bf16* xbf      = (__bf16*)(ws + 65792 + 3145728);       // 2 MB
    __bf16* w13d     = (__bf16*)(ws + 65792 + 3145728 + 2097152);            // 25.2 MB
    __bf16* w2d      = (__bf16*)(ws + 65792 + 3145728 + 2097152 + 25165824); // 12.6 MB
    int*    ctrl     = (int*)(ws + 43057408);                 // 14.5 KB queue/flags

    prep_lite<<<dim3(513), 256, 0, stream>>>(
        x, logits, xbf, counts, base, tok_list, wt_list, ctrl);
    moe_queue<<<dim3(NWORK), 256, 0, stream>>>(
        w13, w13s, w2, w2s, xbf, w13d, w2d,
        counts, base, tok_list, wt_list, act, out, ctrl);
}